// Round 8
// baseline (622.439 us; speedup 1.0000x reference)
//
#include <hip/hip_runtime.h>
#include <math.h>

// Problem constants
#define kN 50000
#define kE 800000
#define kM 4
#define kH 4
#define kC 32
#define kIN 256
#define kD 128   // kH*kC

typedef __attribute__((ext_vector_type(8))) short bf16x8;
typedef __attribute__((ext_vector_type(4))) float f32x4;

__device__ __forceinline__ unsigned int f2bf_pack(float a, float b) {
    unsigned ua = __float_as_uint(a);
    ua += 0x7fffu + ((ua >> 16) & 1u);          // RNE
    unsigned ub = __float_as_uint(b);
    ub += 0x7fffu + ((ub >> 16) & 1u);
    return (ua >> 16) | (ub & 0xffff0000u);
}
__device__ __forceinline__ unsigned short f2bf(float x) {
    unsigned u = __float_as_uint(x);
    u += 0x7fffu + ((u >> 16) & 1u);
    return (unsigned short)(u >> 16);
}

// ---------------------------------------------------------------------------
// Wt16[col][k] = bf16(W[k][col])  (128 cols x 256 k)
__global__ void k_wcast(const float* __restrict__ W, unsigned short* __restrict__ Wt16) {
    const int col = blockIdx.x;        // 0..127
    const int k = threadIdx.x;         // 0..255
    Wt16[(size_t)col * kIN + k] = f2bf(W[(size_t)k * kD + col]);
}

// ---------------------------------------------------------------------------
// FUSED: blocks [0,GEMMB) = MFMA bf16 GEMM (h16 = relu(feats@W+b));
//        blocks [GEMMB, GEMMB+COUNTB) = CSR degree count (independent root).
#define GEMMB ((kN + 127) / 128)          // 391
#define COUNTB (kM * kE / 4 / 256)        // 3125
__global__ __launch_bounds__(256) void k_gemmcount(const float* __restrict__ feats,
                                                   const unsigned short* __restrict__ Wt16,
                                                   const float* __restrict__ b,
                                                   unsigned short* __restrict__ h16,
                                                   const int* __restrict__ ei,
                                                   int* __restrict__ cnt) {
    __shared__ unsigned short fr16[128 * 32];   // 8 KB: A chunk [row][32k]
    const int t = threadIdx.x;

    if (blockIdx.x >= GEMMB) {
        // ---- degree count: 4 edges per thread via int4 ----
        const int i = (blockIdx.x - GEMMB) * 256 + t;
        const int m = i / (kE / 4);
        const int el4 = i - m * (kE / 4);
        const int4 d = *reinterpret_cast<const int4*>(ei + (size_t)m * 2 * kE + kE + el4 * 4);
        atomicAdd(&cnt[m * kN + d.x], 1);
        atomicAdd(&cnt[m * kN + d.y], 1);
        atomicAdd(&cnt[m * kN + d.z], 1);
        atomicAdd(&cnt[m * kN + d.w], 1);
        return;
    }

    // ---- MFMA GEMM ----
    const int lane = t & 63;
    const int wave = t >> 6;
    const int q = lane >> 4;           // quad 0..3
    const int m16 = lane & 15;
    const int wrow = (wave >> 1) * 64;
    const int wcol = (wave & 1) * 64;
    const int rowbase = blockIdx.x * 128;

    f32x4 acc[4][4];
#pragma unroll
    for (int i = 0; i < 4; i++)
#pragma unroll
        for (int j = 0; j < 4; j++) acc[i][j] = (f32x4){0.f, 0.f, 0.f, 0.f};

    const int srow = t >> 3;           // staging: 32 rows per pass
    const int sk4 = t & 7;             // float4 slot along k (8 slots = 32 k)

    for (int kc = 0; kc < kIN; kc += 32) {
        __syncthreads();
#pragma unroll
        for (int it = 0; it < 4; it++) {
            const int row = srow + it * 32;
            const int rg = rowbase + row;
            float4 v = make_float4(0.f, 0.f, 0.f, 0.f);
            if (rg < kN)
                v = *reinterpret_cast<const float4*>(feats + (size_t)rg * kIN + kc + sk4 * 4);
            uint2 p;
            p.x = f2bf_pack(v.x, v.y);
            p.y = f2bf_pack(v.z, v.w);
            *reinterpret_cast<uint2*>(&fr16[row * 32 + sk4 * 4]) = p;
        }
        __syncthreads();

        bf16x8 afr[4], bfr[4];
#pragma unroll
        for (int ri = 0; ri < 4; ri++)
            afr[ri] = *reinterpret_cast<const bf16x8*>(
                &fr16[(wrow + ri * 16 + m16) * 32 + q * 8]);
#pragma unroll
        for (int ci = 0; ci < 4; ci++)
            bfr[ci] = *reinterpret_cast<const bf16x8*>(
                Wt16 + (size_t)(wcol + ci * 16 + m16) * kIN + kc + q * 8);
#pragma unroll
        for (int ri = 0; ri < 4; ri++)
#pragma unroll
            for (int ci = 0; ci < 4; ci++)
                acc[ri][ci] = __builtin_amdgcn_mfma_f32_16x16x32_bf16(
                    afr[ri], bfr[ci], acc[ri][ci], 0, 0, 0);
    }

    float bcol[4];
#pragma unroll
    for (int ci = 0; ci < 4; ci++) bcol[ci] = b[wcol + ci * 16 + m16];

#pragma unroll
    for (int ri = 0; ri < 4; ri++) {
#pragma unroll
        for (int reg = 0; reg < 4; reg++) {
            const int row = rowbase + wrow + ri * 16 + q * 4 + reg;
            if (row < kN) {
#pragma unroll
                for (int ci = 0; ci < 4; ci++) {
                    const int col = wcol + ci * 16 + m16;
                    const float v = fmaxf(acc[ri][ci][reg] + bcol[ci], 0.f);
                    h16[(size_t)row * kD + col] = f2bf(v);
                }
            }
        }
    }
}

// ---------------------------------------------------------------------------
// 3-phase parallel scan blocks
#define SCB 2048
#define SCBLOCKS ((kM * kN + SCB - 1) / SCB)   // 98

// FUSED: blocks [0,SLRB) = per-node attention scalars; [SLRB, SLRB+SCBLOCKS) = bsum.
#define SLRB ((kN * kH + 255) / 256)           // 782
__global__ __launch_bounds__(256) void k_slrsum(const unsigned short* __restrict__ h16,
                                                const float* __restrict__ attn,
                                                float* __restrict__ sl, float* __restrict__ sr,
                                                const int* __restrict__ cnt,
                                                int* __restrict__ bsum) {
    const int t = threadIdx.x;
    if (blockIdx.x >= SLRB) {
        // ---- bsum ----
        const int base = (blockIdx.x - SLRB) * SCB;
        int s = 0;
#pragma unroll
        for (int i = 0; i < 8; i++) {
            const int g = base + t * 8 + i;
            if (g < kM * kN) s += cnt[g];
        }
#pragma unroll
        for (int d = 1; d < 64; d <<= 1) s += __shfl_xor(s, d);
        __shared__ int ws[4];
        if ((t & 63) == 0) ws[t >> 6] = s;
        __syncthreads();
        if (t == 0) bsum[blockIdx.x - SLRB] = ws[0] + ws[1] + ws[2] + ws[3];
        return;
    }
    // ---- slr ----
    const int id = blockIdx.x * 256 + t;
    if (id >= kN * kH) return;
    const int n = id >> 2;
    const int hh = id & 3;
    const unsigned int* hu =
        reinterpret_cast<const unsigned int*>(h16 + (size_t)n * kD + hh * kC);
    unsigned int u[16];
    uint4 u4;
#pragma unroll
    for (int i = 0; i < 4; i++) {
        u4 = reinterpret_cast<const uint4*>(hu)[i];
        u[i * 4 + 0] = u4.x; u[i * 4 + 1] = u4.y; u[i * 4 + 2] = u4.z; u[i * 4 + 3] = u4.w;
    }
    float f0[16], f1[16];
#pragma unroll
    for (int c = 0; c < 16; c++) {
        f0[c] = __uint_as_float(u[c] << 16);
        f1[c] = __uint_as_float(u[c] & 0xffff0000u);
    }
#pragma unroll
    for (int m = 0; m < kM; m++) {
        const float2* al = reinterpret_cast<const float2*>(attn + (m * kH + hh) * 2 * kC);
        const float2* ar = al + 16;
        float s0 = 0.f, s1 = 0.f;
#pragma unroll
        for (int c = 0; c < 16; c++) {
            const float2 a = al[c], r = ar[c];
            s0 += f0[c] * a.x + f1[c] * a.y;
            s1 += f0[c] * r.x + f1[c] * r.y;
        }
        sl[((size_t)m * kN + n) * kH + hh] = s0;
        sr[((size_t)m * kN + n) * kH + hh] = s1;
    }
}

__global__ __launch_bounds__(128) void k_bscan(const int* __restrict__ bsum,
                                               int* __restrict__ bpre,
                                               int* __restrict__ offs) {
    const int t = threadIdx.x;
    const int lane = t & 63, wid = t >> 6;
    int v = (t < SCBLOCKS) ? bsum[t] : 0;
    int incl = v;
#pragma unroll
    for (int d = 1; d < 64; d <<= 1) {
        const int x = __shfl_up(incl, d);
        if (lane >= d) incl += x;
    }
    __shared__ int wt[2];
    if (lane == 63) wt[wid] = incl;
    __syncthreads();
    const int add = (wid == 1) ? wt[0] : 0;
    if (t < SCBLOCKS) bpre[t] = incl - v + add;
    if (t < kM) offs[t * (kN + 1) + kN] = kE;   // per-m sentinel
}

__global__ __launch_bounds__(256) void k_scanout(const int* __restrict__ cnt,
                                                 const int* __restrict__ bpre,
                                                 int* __restrict__ offs) {
    const int base = blockIdx.x * SCB;
    const int t = threadIdx.x;
    const int lane = t & 63, wid = t >> 6;
    int v[8];
    int s = 0;
#pragma unroll
    for (int i = 0; i < 8; i++) {
        const int g = base + t * 8 + i;
        v[i] = (g < kM * kN) ? cnt[g] : 0;
        s += v[i];
    }
    int incl = s;
#pragma unroll
    for (int d = 1; d < 64; d <<= 1) {
        const int x = __shfl_up(incl, d);
        if (lane >= d) incl += x;
    }
    __shared__ int wt[4];
    if (lane == 63) wt[wid] = incl;
    __syncthreads();
    int woff = 0;
#pragma unroll
    for (int i = 0; i < 4; i++)
        if (i < wid) woff += wt[i];
    int run = bpre[blockIdx.x] + woff + (incl - s);
#pragma unroll
    for (int i = 0; i < 8; i++) {
        const int g = base + t * 8 + i;
        if (g < kM * kN) {
            const int m = g / kN;
            const int il = g - m * kN;
            offs[m * (kN + 1) + il] = run - m * kE;
            run += v[i];
        }
    }
}

// ---------------------------------------------------------------------------
// Ticket-based XCD-pinned scatter. Each block reads its real XCD id
// (s_getreg HW_REG_XCC_ID) and claims a chunk ticket from that partition's
// queue; exhausted queues fall back to stealing. Every (partition,chunk)
// ticket is issued exactly once and a block only sees "exhausted" when no
// work remains, so correctness is independent of the XCD mapping. All
// writers of a srcsort line then sit on ONE XCD -> lines assemble fully in
// that L2 (R6/R7: cross-XCD line-splitting caused 14x write amplification).
#define NSWEEP 8
#define SWRANGE (kN / NSWEEP)   // 6250
__global__ __launch_bounds__(256) void k_scatter(const int* __restrict__ ei,
                                                 const int* __restrict__ offs,
                                                 int* __restrict__ cur,
                                                 int* __restrict__ srcsort,
                                                 int* __restrict__ tick) {
    __shared__ int s_part, s_chunk;
    if (threadIdx.x == 0) {
        // HW_REG_XCC_ID = 20, offset 0, size 32 -> imm = 20 | (31<<11)
        int part = (int)(__builtin_amdgcn_s_getreg(20 | (31 << 11)) & 7u);
        int tk = atomicAdd(&tick[part * 16], 1);
        if (tk >= COUNTB) {
            tk = -1;
            for (int q2 = 0; q2 < NSWEEP; q2++) {
                const int t2 = atomicAdd(&tick[q2 * 16], 1);
                if (t2 < COUNTB) { part = q2; tk = t2; break; }
            }
        }
        s_part = part; s_chunk = tk;
    }
    __syncthreads();
    const int tk = s_chunk;
    if (tk < 0) return;
    const int lo = s_part * SWRANGE;
    const int hi = lo + SWRANGE;
    const int i = tk * 256 + threadIdx.x;
    const int m = i / (kE / 4);
    const int el4 = i - m * (kE / 4);
    const int4 s4 = *reinterpret_cast<const int4*>(ei + (size_t)m * 2 * kE + el4 * 4);
    const int4 d4 = *reinterpret_cast<const int4*>(ei + (size_t)m * 2 * kE + kE + el4 * 4);
    const int src[4] = {s4.x, s4.y, s4.z, s4.w};
    const int dst[4] = {d4.x, d4.y, d4.z, d4.w};
#pragma unroll
    for (int j = 0; j < 4; j++) {
        if (dst[j] >= lo && dst[j] < hi) {
            const int pos = offs[m * (kN + 1) + dst[j]] + atomicAdd(&cur[m * kN + dst[j]], 1);
            srcsort[(size_t)m * kE + pos] = src[j];
        }
    }
}

// ---------------------------------------------------------------------------
// aggregation: 4 dsts per block, wave m = metapath m. 8 B/lane gathers:
// 32 lanes cover one h16 row -> each wave gathers TWO edges per load instr
// (8 VMEM/chunk instead of 16). Per-wave epilogues: wave w runs the full
// beta-epilogue for dst-slot w (no 3-idle-wave serialization).
#define CH 16
#define DPB 4
__global__ __launch_bounds__(256) void k_agg(const unsigned short* __restrict__ h16,
                                             const float* __restrict__ sl,
                                             const float* __restrict__ sr,
                                             const int* __restrict__ offs,
                                             const int* __restrict__ srcsort,
                                             const float* __restrict__ ral,
                                             const float* __restrict__ rar,
                                             const float* __restrict__ rbias,
                                             float* __restrict__ out) {
    const int t = threadIdx.x;
    const int m = t >> 6;         // wave = metapath
    const int l = t & 63;
    const int hh = l >> 4;        // weight-producer: head
    const int jj = l & 15;        // weight-producer: edge slot
    const int half = l >> 5;      // gather: edge parity
    const int cl = l & 31;        // gather: channel quad (channels cl*4..cl*4+3)
    const int hg = cl >> 3;       // gather-consumer head
    const int dbase = blockIdx.x * DPB;

    __shared__ float smres[DPB][kM][kD];   // 8 KB
    __shared__ float swts[kM][64];
    __shared__ int sids[kM][CH];

    const char* __restrict__ hb = (const char*)h16;
    const char* __restrict__ srb = (const char*)(sr + (size_t)m * kN * kH);
    const int* __restrict__ sall = srcsort + (size_t)m * kE;

    for (int d = 0; d < DPB; d++) {
        const int dst = dbase + d;
        const int beg = offs[m * (kN + 1) + dst];
        const int cnt = offs[m * (kN + 1) + dst + 1] - beg;
        const int* __restrict__ sbase = sall + beg;
        const float sl_h = sl[((size_t)m * kN + dst) * kH + hh];

        float sum = 0.f, a0 = 0.f, a1 = 0.f, a2 = 0.f, a3 = 0.f;
        const int cfull = cnt & ~(CH - 1);

        for (int c = 0; c < cfull; c += CH) {
            const int my = sbase[c + jj];
            if (l < CH) sids[m][l] = my;
            const float srv = *reinterpret_cast<const float*>(
                srb + (((unsigned int)my << 4) + (hh << 2)));
            float x = sl_h + srv;
            x = x > 0.f ? x : 0.2f * x;       // LeakyReLU(0.2)
            const float w = __expf(x);
            sum += w;
            swts[m][l] = w;                   // layout [hh*16 + jj]
            __builtin_amdgcn_wave_barrier();
#pragma unroll
            for (int g = 0; g < 8; g++) {
                const int eidx = g * 2 + half;
                const int id = sids[m][eidx];
                const float wg = swts[m][hg * 16 + eidx];
                const uint2 u = *reinterpret_cast<const uint2*>(
                    hb + (((unsigned int)id << 8) + (cl << 3)));
                a0 += wg * __uint_as_float(u.x << 16);
                a1 += wg * __uint_as_float(u.x & 0xffff0000u);
                a2 += wg * __uint_as_float(u.y << 16);
                a3 += wg * __uint_as_float(u.y & 0xffff0000u);
            }
            __builtin_amdgcn_wave_barrier();
        }

        if (cfull < cnt) {
            const int c = cfull;
            const int nb = cnt - c;
            const int my = sbase[c + jj];     // over-read: next segment / zeroed slack
            if (l < CH) sids[m][l] = (jj < nb) ? my : dst;   // clamp invalid to hot line
            const float srv = *reinterpret_cast<const float*>(
                srb + (((unsigned int)my << 4) + (hh << 2)));
            float x = sl_h + srv;
            x = x > 0.f ? x : 0.2f * x;
            const float w = (jj < nb) ? __expf(x) : 0.f;
            sum += w;
            swts[m][l] = w;
            __builtin_amdgcn_wave_barrier();
#pragma unroll
            for (int g = 0; g < 8; g++) {
                const int eidx = g * 2 + half;
                const int id = sids[m][eidx];
                const float wg = swts[m][hg * 16 + eidx];
                const uint2 u = *reinterpret_cast<const uint2*>(
                    hb + (((unsigned int)id << 8) + (cl << 3)));
                a0 += wg * __uint_as_float(u.x << 16);
                a1 += wg * __uint_as_float(u.x & 0xffff0000u);
                a2 += wg * __uint_as_float(u.y << 16);
                a3 += wg * __uint_as_float(u.y & 0xffff0000u);
            }
            __builtin_amdgcn_wave_barrier();
        }

        // per-head weight sums (over the 16 lanes of each head group)
        sum += __shfl_xor(sum, 1);
        sum += __shfl_xor(sum, 2);
        sum += __shfl_xor(sum, 4);
        sum += __shfl_xor(sum, 8);
        // merge edge-parity halves of the accumulators
        a0 += __shfl_xor(a0, 32);
        a1 += __shfl_xor(a1, 32);
        a2 += __shfl_xor(a2, 32);
        a3 += __shfl_xor(a3, 32);
        // normalization for this lane's gather head
        const float sumg = __shfl(sum, hg << 4);
        const float inv = 1.0f / (sumg + 1e-16f);
        if (l < 32) {
            float4 r;
            r.x = a0 * inv; r.y = a1 * inv; r.z = a2 * inv; r.w = a3 * inv;
            *reinterpret_cast<float4*>(&smres[d][m][cl * 4]) = r;
        }
    }
    __syncthreads();

    // epilogue: wave m handles dst-slot m
    {
        const int dste = dbase + m;
        const int e0 = l * 2;
        const unsigned int ud = *reinterpret_cast<const unsigned int*>(
            hb + (((unsigned int)dste << 8) + (e0 << 1)));
        const float hd0 = __uint_as_float(ud << 16);
        const float hd1 = __uint_as_float(ud & 0xffff0000u);
        const float bl0 = fmaxf(hd0 * ral[e0], 0.f);
        const float bl1 = fmaxf(hd1 * ral[e0 + 1], 0.f);
        float emb0[5], emb1[5], beta[5];
#pragma unroll
        for (int r = 0; r < 5; r++) {
            float x0, x1;
            if (r < 4) {
                const float2 v = *reinterpret_cast<const float2*>(&smres[m][r][e0]);
                x0 = v.x; x1 = v.y;
            } else {
                x0 = hd0; x1 = hd1;
            }
            emb0[r] = x0;
            emb1[r] = x1;
            const float br0 = fmaxf(x0 * rar[r * kD + e0], 0.f);
            const float br1 = fmaxf(x1 * rar[r * kD + e0 + 1], 0.f);
            float p = bl0 * br0 + bl1 * br1;
            p += __shfl_xor(p, 1);
            p += __shfl_xor(p, 2);
            p += __shfl_xor(p, 4);
            p += __shfl_xor(p, 8);
            beta[r] = p + rbias[r];
        }
        float mx = beta[0];
#pragma unroll
        for (int r = 1; r < 5; r++) mx = fmaxf(mx, beta[r]);
        float s = 0.f, wgt[5];
#pragma unroll
        for (int r = 0; r < 5; r++) { wgt[r] = __expf(beta[r] - mx); s += wgt[r]; }
        const float invb = 1.f / s;
        float o0 = 0.f, o1 = 0.f;
#pragma unroll
        for (int r = 0; r < 5; r++) { o0 += emb0[r] * wgt[r]; o1 += emb1[r] * wgt[r]; }
        out[(size_t)dste * kD + e0] = fmaxf(o0 * invb, 0.f);
        out[(size_t)dste * kD + e0 + 1] = fmaxf(o1 * invb, 0.f);
    }
}

// ---------------------------------------------------------------------------
extern "C" void kernel_launch(void* const* d_in, const int* in_sizes, int n_in,
                              void* d_out, int out_size, void* d_ws, size_t ws_size,
                              hipStream_t stream) {
    const float* feats = (const float*)d_in[0];
    const int* ei      = (const int*)d_in[1];
    const float* W     = (const float*)d_in[2];
    const float* b     = (const float*)d_in[3];
    const float* attn  = (const float*)d_in[4];
    const float* ral   = (const float*)d_in[5];
    const float* rar   = (const float*)d_in[6];
    const float* rbias = (const float*)d_in[7];
    float* out = (float*)d_out;

    char* ws = (char*)d_ws;
    size_t off = 0;
    auto alloc = [&](size_t bytes) -> void* {
        void* p = ws + off;
        off = (off + bytes + 255) & ~(size_t)255;
        return p;
    };
    unsigned short* h16 = (unsigned short*)alloc(sizeof(short) * (size_t)kN * kD); // 12.8 MB
    unsigned short* Wt16= (unsigned short*)alloc(sizeof(short) * (size_t)kD * kIN); // 64 KB
    float* sl   = (float*)alloc(sizeof(float) * (size_t)kM * kN * kH);         // 3.2 MB
    float* sr   = (float*)alloc(sizeof(float) * (size_t)kM * kN * kH);         // 3.2 MB
    int* cnt    = (int*)alloc(sizeof(int) * ((size_t)2 * kM * kN + 128));      // cnt+cur+tick
    int* cur    = cnt + (size_t)kM * kN;
    int* tick   = cnt + (size_t)2 * kM * kN;                                   // 8 padded counters
    int* offs   = (int*)alloc(sizeof(int) * (size_t)kM * (kN + 1));
    int* srcsort= (int*)alloc(sizeof(int) * ((size_t)kM * kE + 64));           // + zeroed slack
    int* bsum   = (int*)alloc(sizeof(int) * SCBLOCKS);
    int* bpre   = (int*)alloc(sizeof(int) * 128);

    hipMemsetAsync(cnt, 0, sizeof(int) * ((size_t)2 * kM * kN + 128), stream);
    hipMemsetAsync(srcsort + (size_t)kM * kE, 0, sizeof(int) * 64, stream);
    k_wcast<<<kD, kIN, 0, stream>>>(W, Wt16);
    k_gemmcount<<<GEMMB + COUNTB, 256, 0, stream>>>(feats, Wt16, b, h16, ei, cnt);
    k_slrsum<<<SLRB + SCBLOCKS, 256, 0, stream>>>(h16, attn, sl, sr, cnt, bsum);
    k_bscan<<<1, 128, 0, stream>>>(bsum, bpre, offs);
    k_scanout<<<SCBLOCKS, 256, 0, stream>>>(cnt, bpre, offs);
    k_scatter<<<NSWEEP * COUNTB, 256, 0, stream>>>(ei, offs, cur, srcsort, tick);
    k_agg<<<kN / DPB, 256, 0, stream>>>(h16, sl, sr, offs, srcsort, ral, rar, rbias, out);
}

// Round 9
// 541.113 us; speedup vs baseline: 1.1503x; 1.1503x over previous
//
#include <hip/hip_runtime.h>
#include <math.h>

// Problem constants
#define kN 50000
#define kE 800000
#define kM 4
#define kH 4
#define kC 32
#define kIN 256
#define kD 128   // kH*kC

typedef __attribute__((ext_vector_type(8))) short bf16x8;
typedef __attribute__((ext_vector_type(4))) float f32x4;

__device__ __forceinline__ unsigned int f2bf_pack(float a, float b) {
    unsigned ua = __float_as_uint(a);
    ua += 0x7fffu + ((ua >> 16) & 1u);          // RNE
    unsigned ub = __float_as_uint(b);
    ub += 0x7fffu + ((ub >> 16) & 1u);
    return (ua >> 16) | (ub & 0xffff0000u);
}
__device__ __forceinline__ unsigned short f2bf(float x) {
    unsigned u = __float_as_uint(x);
    u += 0x7fffu + ((u >> 16) & 1u);
    return (unsigned short)(u >> 16);
}

// ---------------------------------------------------------------------------
// Wt16[col][k] = bf16(W[k][col])  (128 cols x 256 k)
__global__ void k_wcast(const float* __restrict__ W, unsigned short* __restrict__ Wt16) {
    const int col = blockIdx.x;        // 0..127
    const int k = threadIdx.x;         // 0..255
    Wt16[(size_t)col * kIN + k] = f2bf(W[(size_t)k * kD + col]);
}

// ---------------------------------------------------------------------------
// FUSED: blocks [0,GEMMB) = MFMA bf16 GEMM (h16 = relu(feats@W+b));
//        blocks [GEMMB, GEMMB+COUNTB) = CSR degree count (independent root).
#define GEMMB ((kN + 127) / 128)          // 391
#define COUNTB (kM * kE / 4 / 256)        // 3125
__global__ __launch_bounds__(256) void k_gemmcount(const float* __restrict__ feats,
                                                   const unsigned short* __restrict__ Wt16,
                                                   const float* __restrict__ b,
                                                   unsigned short* __restrict__ h16,
                                                   const int* __restrict__ ei,
                                                   int* __restrict__ cnt) {
    __shared__ unsigned short fr16[128 * 32];   // 8 KB: A chunk [row][32k]
    const int t = threadIdx.x;

    if (blockIdx.x >= GEMMB) {
        // ---- degree count: 4 edges per thread via int4 ----
        const int i = (blockIdx.x - GEMMB) * 256 + t;
        const int m = i / (kE / 4);
        const int el4 = i - m * (kE / 4);
        const int4 d = *reinterpret_cast<const int4*>(ei + (size_t)m * 2 * kE + kE + el4 * 4);
        atomicAdd(&cnt[m * kN + d.x], 1);
        atomicAdd(&cnt[m * kN + d.y], 1);
        atomicAdd(&cnt[m * kN + d.z], 1);
        atomicAdd(&cnt[m * kN + d.w], 1);
        return;
    }

    // ---- MFMA GEMM ----
    const int lane = t & 63;
    const int wave = t >> 6;
    const int q = lane >> 4;           // quad 0..3
    const int m16 = lane & 15;
    const int wrow = (wave >> 1) * 64;
    const int wcol = (wave & 1) * 64;
    const int rowbase = blockIdx.x * 128;

    f32x4 acc[4][4];
#pragma unroll
    for (int i = 0; i < 4; i++)
#pragma unroll
        for (int j = 0; j < 4; j++) acc[i][j] = (f32x4){0.f, 0.f, 0.f, 0.f};

    const int srow = t >> 3;           // staging: 32 rows per pass
    const int sk4 = t & 7;             // float4 slot along k (8 slots = 32 k)

    for (int kc = 0; kc < kIN; kc += 32) {
        __syncthreads();
#pragma unroll
        for (int it = 0; it < 4; it++) {
            const int row = srow + it * 32;
            const int rg = rowbase + row;
            float4 v = make_float4(0.f, 0.f, 0.f, 0.f);
            if (rg < kN)
                v = *reinterpret_cast<const float4*>(feats + (size_t)rg * kIN + kc + sk4 * 4);
            uint2 p;
            p.x = f2bf_pack(v.x, v.y);
            p.y = f2bf_pack(v.z, v.w);
            *reinterpret_cast<uint2*>(&fr16[row * 32 + sk4 * 4]) = p;
        }
        __syncthreads();

        bf16x8 afr[4], bfr[4];
#pragma unroll
        for (int ri = 0; ri < 4; ri++)
            afr[ri] = *reinterpret_cast<const bf16x8*>(
                &fr16[(wrow + ri * 16 + m16) * 32 + q * 8]);
#pragma unroll
        for (int ci = 0; ci < 4; ci++)
            bfr[ci] = *reinterpret_cast<const bf16x8*>(
                Wt16 + (size_t)(wcol + ci * 16 + m16) * kIN + kc + q * 8);
#pragma unroll
        for (int ri = 0; ri < 4; ri++)
#pragma unroll
            for (int ci = 0; ci < 4; ci++)
                acc[ri][ci] = __builtin_amdgcn_mfma_f32_16x16x32_bf16(
                    afr[ri], bfr[ci], acc[ri][ci], 0, 0, 0);
    }

    float bcol[4];
#pragma unroll
    for (int ci = 0; ci < 4; ci++) bcol[ci] = b[wcol + ci * 16 + m16];

#pragma unroll
    for (int ri = 0; ri < 4; ri++) {
#pragma unroll
        for (int reg = 0; reg < 4; reg++) {
            const int row = rowbase + wrow + ri * 16 + q * 4 + reg;
            if (row < kN) {
#pragma unroll
                for (int ci = 0; ci < 4; ci++) {
                    const int col = wcol + ci * 16 + m16;
                    const float v = fmaxf(acc[ri][ci][reg] + bcol[ci], 0.f);
                    h16[(size_t)row * kD + col] = f2bf(v);
                }
            }
        }
    }
}

// ---------------------------------------------------------------------------
// 3-phase parallel scan blocks
#define SCB 2048
#define SCBLOCKS ((kM * kN + SCB - 1) / SCB)   // 98

// FUSED: blocks [0,SLRB) = per-node attention scalars; [SLRB, SLRB+SCBLOCKS) = bsum.
#define SLRB ((kN * kH + 255) / 256)           // 782
__global__ __launch_bounds__(256) void k_slrsum(const unsigned short* __restrict__ h16,
                                                const float* __restrict__ attn,
                                                float* __restrict__ sl, float* __restrict__ sr,
                                                const int* __restrict__ cnt,
                                                int* __restrict__ bsum) {
    const int t = threadIdx.x;
    if (blockIdx.x >= SLRB) {
        // ---- bsum ----
        const int base = (blockIdx.x - SLRB) * SCB;
        int s = 0;
#pragma unroll
        for (int i = 0; i < 8; i++) {
            const int g = base + t * 8 + i;
            if (g < kM * kN) s += cnt[g];
        }
#pragma unroll
        for (int d = 1; d < 64; d <<= 1) s += __shfl_xor(s, d);
        __shared__ int ws[4];
        if ((t & 63) == 0) ws[t >> 6] = s;
        __syncthreads();
        if (t == 0) bsum[blockIdx.x - SLRB] = ws[0] + ws[1] + ws[2] + ws[3];
        return;
    }
    // ---- slr ----
    const int id = blockIdx.x * 256 + t;
    if (id >= kN * kH) return;
    const int n = id >> 2;
    const int hh = id & 3;
    const unsigned int* hu =
        reinterpret_cast<const unsigned int*>(h16 + (size_t)n * kD + hh * kC);
    unsigned int u[16];
    uint4 u4;
#pragma unroll
    for (int i = 0; i < 4; i++) {
        u4 = reinterpret_cast<const uint4*>(hu)[i];
        u[i * 4 + 0] = u4.x; u[i * 4 + 1] = u4.y; u[i * 4 + 2] = u4.z; u[i * 4 + 3] = u4.w;
    }
    float f0[16], f1[16];
#pragma unroll
    for (int c = 0; c < 16; c++) {
        f0[c] = __uint_as_float(u[c] << 16);
        f1[c] = __uint_as_float(u[c] & 0xffff0000u);
    }
#pragma unroll
    for (int m = 0; m < kM; m++) {
        const float2* al = reinterpret_cast<const float2*>(attn + (m * kH + hh) * 2 * kC);
        const float2* ar = al + 16;
        float s0 = 0.f, s1 = 0.f;
#pragma unroll
        for (int c = 0; c < 16; c++) {
            const float2 a = al[c], r = ar[c];
            s0 += f0[c] * a.x + f1[c] * a.y;
            s1 += f0[c] * r.x + f1[c] * r.y;
        }
        sl[((size_t)m * kN + n) * kH + hh] = s0;
        sr[((size_t)m * kN + n) * kH + hh] = s1;
    }
}

__global__ __launch_bounds__(128) void k_bscan(const int* __restrict__ bsum,
                                               int* __restrict__ bpre,
                                               int* __restrict__ offs) {
    const int t = threadIdx.x;
    const int lane = t & 63, wid = t >> 6;
    int v = (t < SCBLOCKS) ? bsum[t] : 0;
    int incl = v;
#pragma unroll
    for (int d = 1; d < 64; d <<= 1) {
        const int x = __shfl_up(incl, d);
        if (lane >= d) incl += x;
    }
    __shared__ int wt[2];
    if (lane == 63) wt[wid] = incl;
    __syncthreads();
    const int add = (wid == 1) ? wt[0] : 0;
    if (t < SCBLOCKS) bpre[t] = incl - v + add;
    if (t < kM) offs[t * (kN + 1) + kN] = kE;   // per-m sentinel
}

__global__ __launch_bounds__(256) void k_scanout(const int* __restrict__ cnt,
                                                 const int* __restrict__ bpre,
                                                 int* __restrict__ offs) {
    const int base = blockIdx.x * SCB;
    const int t = threadIdx.x;
    const int lane = t & 63, wid = t >> 6;
    int v[8];
    int s = 0;
#pragma unroll
    for (int i = 0; i < 8; i++) {
        const int g = base + t * 8 + i;
        v[i] = (g < kM * kN) ? cnt[g] : 0;
        s += v[i];
    }
    int incl = s;
#pragma unroll
    for (int d = 1; d < 64; d <<= 1) {
        const int x = __shfl_up(incl, d);
        if (lane >= d) incl += x;
    }
    __shared__ int wt[4];
    if (lane == 63) wt[wid] = incl;
    __syncthreads();
    int woff = 0;
#pragma unroll
    for (int i = 0; i < 4; i++)
        if (i < wid) woff += wt[i];
    int run = bpre[blockIdx.x] + woff + (incl - s);
#pragma unroll
    for (int i = 0; i < 8; i++) {
        const int g = base + t * 8 + i;
        if (g < kM * kN) {
            const int m = g / kN;
            const int il = g - m * kN;
            offs[m * (kN + 1) + il] = run - m * kE;
            run += v[i];
        }
    }
}

// ---------------------------------------------------------------------------
// Two-phase bucket sort replacing the one-pass scatter.
// Phase A: stream edges once, LDS-histogram into 98 dst-buckets (dst>>9),
// reserve space with ~98 amortized global atomics per block, write packed
// (dstlocal<<16 | src) u32 pairs grouped by bucket (CSR-aligned via offs).
#define NBK 98                        // buckets: dst>>9, 512 dsts each
#define PAB ((kE + 4095) / 4096)      // 196 chunks per metapath
__global__ __launch_bounds__(256) void k_bucket(const int* __restrict__ ei,
                                                const int* __restrict__ offs,
                                                int* __restrict__ bcur,
                                                unsigned int* __restrict__ pairs) {
    __shared__ int hist[NBK], base[NBK], h2[NBK], bstart[NBK];
    const int t = threadIdx.x;
    const int m = blockIdx.x / PAB;
    const int chunk = blockIdx.x - m * PAB;
    const int e0 = chunk * 4096;
    for (int j = t; j < NBK; j += 256) { hist[j] = 0; h2[j] = 0; }
    __syncthreads();
    int src[16], dst[16];
#pragma unroll
    for (int i = 0; i < 16; i++) {
        const int e = e0 + i * 256 + t;
        const int eok = (e < kE) ? e : 0;
        src[i] = ei[(size_t)m * 2 * kE + eok];
        dst[i] = (e < kE) ? ei[(size_t)m * 2 * kE + kE + eok] : -1;
    }
#pragma unroll
    for (int i = 0; i < 16; i++)
        if (dst[i] >= 0) atomicAdd(&hist[dst[i] >> 9], 1);
    __syncthreads();
    for (int j = t; j < NBK; j += 256) {
        base[j] = atomicAdd(&bcur[m * NBK + j], hist[j]);
        bstart[j] = offs[m * (kN + 1) + (j << 9)];
    }
    __syncthreads();
#pragma unroll
    for (int i = 0; i < 16; i++) {
        if (dst[i] >= 0) {
            const int bk = dst[i] >> 9;
            const int slot = base[bk] + atomicAdd(&h2[bk], 1);
            pairs[(size_t)m * kE + bstart[bk] + slot] =
                ((unsigned int)(dst[i] & 511) << 16) | (unsigned int)src[i];
        }
    }
}

// Phase B: one block per (m,bucket) -> srcsort writes confined to a 32 KB
// window with a SINGLE writer block (one XCD) -> lines fully assembled in
// that L2, no cross-XCD splitting. 8-deep batched independent atomics.
__global__ __launch_bounds__(256) void k_sortb(const unsigned int* __restrict__ pairs,
                                               const int* __restrict__ offs,
                                               int* __restrict__ cur,
                                               int* __restrict__ srcsort) {
    const int t = threadIdx.x;
    const int m = blockIdx.x / NBK;
    const int bk = blockIdx.x - m * NBK;
    const int bs = bk << 9;
    const int be = (bs + 512 < kN) ? (bs + 512) : kN;
    const int* __restrict__ om = offs + m * (kN + 1);
    const int start = om[bs];
    const int end = om[be];
    int* __restrict__ cm = cur + m * kN;
    for (int c = start; c < end; c += 2048) {
        unsigned int v[8]; int pos[8]; bool ok[8];
#pragma unroll
        for (int j = 0; j < 8; j++) {
            const int idx = c + j * 256 + t;
            ok[j] = idx < end;
            v[j] = pairs[(size_t)m * kE + (ok[j] ? idx : start)];
        }
#pragma unroll
        for (int j = 0; j < 8; j++) {
            if (ok[j]) {
                const int d = bs + (int)(v[j] >> 16);
                pos[j] = om[d] + atomicAdd(&cm[d], 1);
            }
        }
#pragma unroll
        for (int j = 0; j < 8; j++)
            if (ok[j]) srcsort[(size_t)m * kE + pos[j]] = (int)(v[j] & 0xffffu);
    }
}

// ---------------------------------------------------------------------------
// aggregation (R7-proven version): per-dst block, wave m = metapath m.
// No max-shift softmax; cooperative weights via wave-local LDS broadcast;
// branch-free full chunks (16 gathers in flight); tail clamps to dst.
#define CH 16
__global__ __launch_bounds__(256) void k_agg(const unsigned short* __restrict__ h16,
                                             const float* __restrict__ sl,
                                             const float* __restrict__ sr,
                                             const int* __restrict__ offs,
                                             const int* __restrict__ srcsort,
                                             const float* __restrict__ ral,
                                             const float* __restrict__ rar,
                                             const float* __restrict__ rbias,
                                             float* __restrict__ out) {
    const int dst = blockIdx.x;
    const int t = threadIdx.x;
    const int m = t >> 6;
    const int l = t & 63;
    const int hh = l >> 4;        // head for this lane
    const int jj = l & 15;        // edge slot this lane computes the weight for
    const int e0 = l * 2;         // channel pair e0, e0+1

    __shared__ float smres[kM][kD];
    __shared__ float swts[kM][64];
    __shared__ int sids[kM][64];

    const int beg = offs[m * (kN + 1) + dst];
    const int cnt = offs[m * (kN + 1) + dst + 1] - beg;
    const float sl_h = sl[((size_t)m * kN + dst) * kH + hh];
    const int* __restrict__ sbase = srcsort + (size_t)m * kE + beg;
    const char* __restrict__ hb = (const char*)h16;
    const char* __restrict__ srb = (const char*)(sr + (size_t)m * kN * kH);
    const unsigned int ebyte = (unsigned int)(e0 << 1);
    const unsigned int hbyte = (unsigned int)(hh << 2);

    float sum = 0.f, a0 = 0.f, a1 = 0.f;
    const int cfull = cnt & ~(CH - 1);

    for (int c = 0; c < cfull; c += CH) {
        const int my = sbase[c + jj];
        sids[m][l] = my;
        const float srv = *reinterpret_cast<const float*>(
            srb + (((unsigned int)my << 4) + hbyte));
        __builtin_amdgcn_wave_barrier();
        int sj[CH];
        *reinterpret_cast<int4*>(&sj[0])  = *reinterpret_cast<const int4*>(&sids[m][0]);
        *reinterpret_cast<int4*>(&sj[4])  = *reinterpret_cast<const int4*>(&sids[m][4]);
        *reinterpret_cast<int4*>(&sj[8])  = *reinterpret_cast<const int4*>(&sids[m][8]);
        *reinterpret_cast<int4*>(&sj[12]) = *reinterpret_cast<const int4*>(&sids[m][12]);
        float x = sl_h + srv;
        x = x > 0.f ? x : 0.2f * x;            // LeakyReLU(0.2)
        const float w = __expf(x);
        sum += w;
        swts[m][l] = w;
        __builtin_amdgcn_wave_barrier();
        const float4 w0 = *reinterpret_cast<const float4*>(&swts[m][hh * 16]);
        const float4 w1 = *reinterpret_cast<const float4*>(&swts[m][hh * 16 + 4]);
        const float4 w2 = *reinterpret_cast<const float4*>(&swts[m][hh * 16 + 8]);
        const float4 w3 = *reinterpret_cast<const float4*>(&swts[m][hh * 16 + 12]);
        __builtin_amdgcn_wave_barrier();
        unsigned int u[CH];
#pragma unroll
        for (int j = 0; j < CH; j++)
            u[j] = *reinterpret_cast<const unsigned int*>(
                hb + (((unsigned int)sj[j] << 8) + ebyte));
        const float wj[CH] = {w0.x, w0.y, w0.z, w0.w, w1.x, w1.y, w1.z, w1.w,
                              w2.x, w2.y, w2.z, w2.w, w3.x, w3.y, w3.z, w3.w};
#pragma unroll
        for (int j = 0; j < CH; j++) {
            a0 += wj[j] * __uint_as_float(u[j] << 16);
            a1 += wj[j] * __uint_as_float(u[j] & 0xffff0000u);
        }
    }

    if (cfull < cnt) {
        const int c = cfull;
        const int my = sbase[c + jj];          // over-read lands in next segment / zeroed slack
        sids[m][l] = my;
        const float srv = *reinterpret_cast<const float*>(
            srb + (((unsigned int)my << 4) + hbyte));
        __builtin_amdgcn_wave_barrier();
        int sj[CH];
        *reinterpret_cast<int4*>(&sj[0])  = *reinterpret_cast<const int4*>(&sids[m][0]);
        *reinterpret_cast<int4*>(&sj[4])  = *reinterpret_cast<const int4*>(&sids[m][4]);
        *reinterpret_cast<int4*>(&sj[8])  = *reinterpret_cast<const int4*>(&sids[m][8]);
        *reinterpret_cast<int4*>(&sj[12]) = *reinterpret_cast<const int4*>(&sids[m][12]);
        float x = sl_h + srv;
        x = x > 0.f ? x : 0.2f * x;
        const float w = (c + jj < cnt) ? __expf(x) : 0.f;
        sum += w;
        swts[m][l] = w;
        __builtin_amdgcn_wave_barrier();
        const float4 w0 = *reinterpret_cast<const float4*>(&swts[m][hh * 16]);
        const float4 w1 = *reinterpret_cast<const float4*>(&swts[m][hh * 16 + 4]);
        const float4 w2 = *reinterpret_cast<const float4*>(&swts[m][hh * 16 + 8]);
        const float4 w3 = *reinterpret_cast<const float4*>(&swts[m][hh * 16 + 12]);
        __builtin_amdgcn_wave_barrier();
        const int nb = cnt - c;
#pragma unroll
        for (int j = 0; j < CH; j++) sj[j] = (j < nb) ? sj[j] : dst;
        unsigned int u[CH];
#pragma unroll
        for (int j = 0; j < CH; j++)
            u[j] = *reinterpret_cast<const unsigned int*>(
                hb + (((unsigned int)sj[j] << 8) + ebyte));
        const float wj[CH] = {w0.x, w0.y, w0.z, w0.w, w1.x, w1.y, w1.z, w1.w,
                              w2.x, w2.y, w2.z, w2.w, w3.x, w3.y, w3.z, w3.w};
#pragma unroll
        for (int j = 0; j < CH; j++) {
            a0 += wj[j] * __uint_as_float(u[j] << 16);
            a1 += wj[j] * __uint_as_float(u[j] & 0xffff0000u);
        }
    }

    sum += __shfl_xor(sum, 1);
    sum += __shfl_xor(sum, 2);
    sum += __shfl_xor(sum, 4);
    sum += __shfl_xor(sum, 8);
    const float inv = 1.0f / (sum + 1e-16f);
    smres[m][e0] = a0 * inv;
    smres[m][e0 + 1] = a1 * inv;
    __syncthreads();

    if (m == 0) {
        const unsigned int ud = *reinterpret_cast<const unsigned int*>(
            hb + (((unsigned int)dst << 8) + ebyte));
        const float hd0 = __uint_as_float(ud << 16);
        const float hd1 = __uint_as_float(ud & 0xffff0000u);
        const float bl0 = fmaxf(hd0 * ral[e0], 0.f);
        const float bl1 = fmaxf(hd1 * ral[e0 + 1], 0.f);
        float emb0[5], emb1[5], beta[5];
#pragma unroll
        for (int r = 0; r < 5; r++) {
            const float x0 = (r < 4) ? smres[r][e0] : hd0;
            const float x1 = (r < 4) ? smres[r][e0 + 1] : hd1;
            emb0[r] = x0;
            emb1[r] = x1;
            const float br0 = fmaxf(x0 * rar[r * kD + e0], 0.f);
            const float br1 = fmaxf(x1 * rar[r * kD + e0 + 1], 0.f);
            float p = bl0 * br0 + bl1 * br1;
            p += __shfl_xor(p, 1);
            p += __shfl_xor(p, 2);
            p += __shfl_xor(p, 4);
            p += __shfl_xor(p, 8);
            beta[r] = p + rbias[r];
        }
        float mx = beta[0];
#pragma unroll
        for (int r = 1; r < 5; r++) mx = fmaxf(mx, beta[r]);
        float s = 0.f, wgt[5];
#pragma unroll
        for (int r = 0; r < 5; r++) { wgt[r] = __expf(beta[r] - mx); s += wgt[r]; }
        const float invb = 1.f / s;
        float o0 = 0.f, o1 = 0.f;
#pragma unroll
        for (int r = 0; r < 5; r++) { o0 += emb0[r] * wgt[r]; o1 += emb1[r] * wgt[r]; }
        out[(size_t)dst * kD + e0] = fmaxf(o0 * invb, 0.f);
        out[(size_t)dst * kD + e0 + 1] = fmaxf(o1 * invb, 0.f);
    }
}

// ---------------------------------------------------------------------------
extern "C" void kernel_launch(void* const* d_in, const int* in_sizes, int n_in,
                              void* d_out, int out_size, void* d_ws, size_t ws_size,
                              hipStream_t stream) {
    const float* feats = (const float*)d_in[0];
    const int* ei      = (const int*)d_in[1];
    const float* W     = (const float*)d_in[2];
    const float* b     = (const float*)d_in[3];
    const float* attn  = (const float*)d_in[4];
    const float* ral   = (const float*)d_in[5];
    const float* rar   = (const float*)d_in[6];
    const float* rbias = (const float*)d_in[7];
    float* out = (float*)d_out;

    char* ws = (char*)d_ws;
    size_t off = 0;
    auto alloc = [&](size_t bytes) -> void* {
        void* p = ws + off;
        off = (off + bytes + 255) & ~(size_t)255;
        return p;
    };
    unsigned short* h16 = (unsigned short*)alloc(sizeof(short) * (size_t)kN * kD); // 12.8 MB
    unsigned short* Wt16= (unsigned short*)alloc(sizeof(short) * (size_t)kD * kIN); // 64 KB
    float* sl   = (float*)alloc(sizeof(float) * (size_t)kM * kN * kH);         // 3.2 MB
    float* sr   = (float*)alloc(sizeof(float) * (size_t)kM * kN * kH);         // 3.2 MB
    int* cnt    = (int*)alloc(sizeof(int) * ((size_t)2 * kM * kN + 512));      // cnt+cur+bcur
    int* cur    = cnt + (size_t)kM * kN;
    int* bcur   = cnt + (size_t)2 * kM * kN;                                   // kM*NBK = 392
    int* offs   = (int*)alloc(sizeof(int) * (size_t)kM * (kN + 1));
    int* srcsort= (int*)alloc(sizeof(int) * ((size_t)kM * kE + 64));           // + zeroed slack
    unsigned int* pairs = (unsigned int*)alloc(sizeof(int) * (size_t)kM * kE); // 12.8 MB
    int* bsum   = (int*)alloc(sizeof(int) * SCBLOCKS);
    int* bpre   = (int*)alloc(sizeof(int) * 128);

    hipMemsetAsync(cnt, 0, sizeof(int) * ((size_t)2 * kM * kN + 512), stream);
    hipMemsetAsync(srcsort + (size_t)kM * kE, 0, sizeof(int) * 64, stream);
    k_wcast<<<kD, kIN, 0, stream>>>(W, Wt16);
    k_gemmcount<<<GEMMB + COUNTB, 256, 0, stream>>>(feats, Wt16, b, h16, ei, cnt);
    k_slrsum<<<SLRB + SCBLOCKS, 256, 0, stream>>>(h16, attn, sl, sr, cnt, bsum);
    k_bscan<<<1, 128, 0, stream>>>(bsum, bpre, offs);
    k_scanout<<<SCBLOCKS, 256, 0, stream>>>(cnt, bpre, offs);
    k_bucket<<<kM * PAB, 256, 0, stream>>>(ei, offs, bcur, pairs);
    k_sortb<<<kM * NBK, 256, 0, stream>>>(pairs, offs, cur, srcsort);
    k_agg<<<kN, 256, 0, stream>>>(h16, sl, sr, offs, srcsort, ral, rar, rbias, out);
}